// Round 6
// baseline (122.032 us; speedup 1.0000x reference)
//
#include <hip/hip_runtime.h>

#if defined(__has_builtin)
#if __has_builtin(__builtin_amdgcn_exp2f)
#define EXP2F(x) __builtin_amdgcn_exp2f(x)
#endif
#if __has_builtin(__builtin_amdgcn_fdot2)
#define HAVE_FDOT2 1
#endif
#endif
#ifndef EXP2F
#define EXP2F(x) exp2f(x)
#endif

#define BLOCK 256
#define QPT 8          // queries per thread
#define TILE 512       // train points staged per iteration (TILE/2 pairs)
#define TILE2 (TILE / 2)
#define MAX_SEGS 256
#define RSPLIT 4       // seg-parallelism per query in the reduce

typedef float v2f __attribute__((ext_vector_type(2)));
typedef _Float16 h2 __attribute__((ext_vector_type(2)));

// scores = -0.5*((q-x)*w)^2 ; fold sqrt(0.5*log2(e)) into w so exp2 applies
// directly: exp2(-(t*t)) with t = fma(q, a, nb), a = w*K, nb = -x*w*K.
#define KFOLD 0.8493218f  // sqrt(0.5 * log2(e))

__global__ __launch_bounds__(BLOCK) void nw_partial(
    const float* __restrict__ q, const float* __restrict__ xt,
    const float* __restrict__ yt, const float* __restrict__ w,
    float2* __restrict__ partial, int n_q, int n_t, int segs)
{
    // SoA pair layout: one ds_read_b128 yields {a0,a1} and {nb0,nb1} as
    // aligned VGPR pairs for v_pk_fma_f32 with zero splat movs.
    __shared__ float4 tileA[TILE2];        // {a_j, a_j+1, nb_j, nb_j+1}
    __shared__ unsigned int tileY[TILE2];  // half2 {y_j, y_j+1} (RNE)

    const int seg = blockIdx.x;
    const int tid = threadIdx.x;
    const int qbase = blockIdx.y * (BLOCK * QPT) + tid;

    v2f q2[QPT];     // {q_i, q_i} splat, hoisted (loop-invariant)
    float num[QPT], den[QPT];
#pragma unroll
    for (int i = 0; i < QPT; ++i) {
        int qi = qbase + i * BLOCK;
        float qv = (qi < n_q) ? q[qi] : 0.f;
        q2[i] = (v2f){qv, qv};
        num[i] = 0.f;
        den[i] = 0.f;
    }

    const int seg_len = (n_t + segs - 1) / segs;
    const int s0 = seg * seg_len;
    const int s1 = min(s0 + seg_len, n_t);

    const h2 one2 = {(_Float16)1.0f, (_Float16)1.0f};

    for (int base = s0; base < s1; base += TILE) {
        const int cnt = min(TILE, s1 - base);
        const int cnt2 = (cnt + 1) >> 1;
        __syncthreads();
        for (int j2 = tid; j2 < cnt2; j2 += BLOCK) {
            int j0 = base + 2 * j2;
            int j1 = j0 + 1;
            float a0 = w[j0] * KFOLD;
            float nb0 = -xt[j0] * a0;
            float y0 = yt[j0];
            float a1 = 0.f, nb1 = 1.0e4f, y1 = 0.f;  // pad: e=exp2(-1e8)=0
            if (j1 < s1) {
                a1 = w[j1] * KFOLD;
                nb1 = -xt[j1] * a1;
                y1 = yt[j1];
            }
            tileA[j2] = make_float4(a0, a1, nb0, nb1);
            h2 yh = {(_Float16)y0, (_Float16)y1};
            tileY[j2] = __builtin_bit_cast(unsigned int, yh);
        }
        __syncthreads();
#pragma unroll 2
        for (int j2 = 0; j2 < cnt2; ++j2) {
            float4 A = tileA[j2];
            v2f a2 = (v2f){A.x, A.y};
            v2f nb2 = (v2f){A.z, A.w};
            h2 yh = __builtin_bit_cast(h2, tileY[j2]);
#ifndef HAVE_FDOT2
            float yf0 = (float)yh.x, yf1 = (float)yh.y;
#endif
#pragma unroll
            for (int i = 0; i < QPT; ++i) {
                v2f t = __builtin_elementwise_fma(q2[i], a2, nb2);
                v2f s = -(t * t);            // v_pk_mul_f32 with neg
                float e0 = EXP2F(s.x);
                float e1 = EXP2F(s.y);
#ifdef HAVE_FDOT2
                h2 ep = __builtin_bit_cast(h2, __builtin_amdgcn_cvt_pkrtz(e0, e1));
                num[i] = __builtin_amdgcn_fdot2(ep, yh, num[i], false);
                den[i] = __builtin_amdgcn_fdot2(ep, one2, den[i], false);
#else
                num[i] = fmaf(e0, yf0, fmaf(e1, yf1, num[i]));
                den[i] += e0 + e1;
#endif
            }
        }
    }

#pragma unroll
    for (int i = 0; i < QPT; ++i) {
        int qi = qbase + i * BLOCK;
        if (qi < n_q) partial[seg * n_q + qi] = make_float2(num[i], den[i]);
    }
}

// Block handles 64 queries; RSPLIT waves split the segs dimension so each
// wave's 64 lanes read 64 consecutive qi -> fully coalesced.
__global__ __launch_bounds__(BLOCK) void nw_reduce(
    const float2* __restrict__ partial, float* __restrict__ out,
    int n_q, int segs)
{
    __shared__ float2 red[RSPLIT][64];
    const int tid = threadIdx.x;
    const int c = tid >> 6;          // 0..3 (seg chunk = wave index)
    const int ql = tid & 63;         // query within block
    const int qi = blockIdx.x * 64 + ql;

    float num = 0.f, den = 0.f;
    if (qi < n_q) {
        for (int s = c; s < segs; s += RSPLIT) {
            float2 p = partial[(size_t)s * n_q + qi];
            num += p.x;
            den += p.y;
        }
    }
    red[c][ql] = make_float2(num, den);
    __syncthreads();
    if (c == 0 && qi < n_q) {
        float2 r1 = red[1][ql], r2 = red[2][ql], r3 = red[3][ql];
        num += r1.x + r2.x + r3.x;
        den += r1.y + r2.y + r3.y;
        out[qi] = num / den;
    }
}

extern "C" void kernel_launch(void* const* d_in, const int* in_sizes, int n_in,
                              void* d_out, int out_size, void* d_ws, size_t ws_size,
                              hipStream_t stream) {
    const float* q  = (const float*)d_in[0];
    const float* xt = (const float*)d_in[1];
    const float* yt = (const float*)d_in[2];
    const float* w  = (const float*)d_in[3];
    const int n_q = in_sizes[0];
    const int n_t = in_sizes[1];

    // split-K segments, clamped so partials fit in the workspace
    int segs = MAX_SEGS;
    size_t need = (size_t)segs * (size_t)n_q * sizeof(float2);
    if (need > ws_size) {
        segs = (int)(ws_size / ((size_t)n_q * sizeof(float2)));
        if (segs < 1) segs = 1;
    }

    float2* partial = (float2*)d_ws;
    dim3 grid(segs, (n_q + BLOCK * QPT - 1) / (BLOCK * QPT));
    nw_partial<<<grid, BLOCK, 0, stream>>>(q, xt, yt, w, partial, n_q, n_t, segs);
    nw_reduce<<<(n_q + 63) / 64, BLOCK, 0, stream>>>(partial, (float*)d_out,
                                                     n_q, segs);
}

// Round 7
// 105.176 us; speedup vs baseline: 1.1603x; 1.1603x over previous
//
#include <hip/hip_runtime.h>

#if defined(__has_builtin)
#if __has_builtin(__builtin_amdgcn_exp2f)
#define EXP2F(x) __builtin_amdgcn_exp2f(x)
#endif
#endif
#ifndef EXP2F
#define EXP2F(x) exp2f(x)
#endif

#define BLOCK 256
#define QPT 8          // queries per thread
#define TILE 512       // max train points staged per iteration
#define TILE2 (TILE / 2)
#define MAX_SEGS 128
#define RSPLIT 4       // seg-parallelism per query in the reduce

typedef float v2f __attribute__((ext_vector_type(2)));

// scores = -0.5*((q-x)*w)^2 ; fold sqrt(0.5*log2(e)) into w so exp2 applies
// directly: exp2(-(t*t)) with t = fma(q, a, nb), a = w*K, nb = -x*w*K.
#define KFOLD 0.8493218f  // sqrt(0.5 * log2(e))

__global__ __launch_bounds__(BLOCK) void nw_partial(
    const float* __restrict__ q, const float* __restrict__ xt,
    const float* __restrict__ yt, const float* __restrict__ w,
    float2* __restrict__ partial, int n_q, int n_t, int segs)
{
    // SoA pair layout: ds_read_b128 yields {a0,a1},{nb0,nb1} aligned for
    // v_pk_fma_f32; ds_read_b64 yields {y0,y1} for the packed accumulate.
    __shared__ float4 tileA[TILE2];   // {a_j, a_j+1, nb_j, nb_j+1}
    __shared__ float2 tileY[TILE2];   // {y_j, y_j+1}

    const int seg = blockIdx.x;
    const int tid = threadIdx.x;
    const int qbase = blockIdx.y * (BLOCK * QPT) + tid;

    v2f q2[QPT];       // {q_i, q_i} splat, loop-invariant
    v2f num2[QPT], den2[QPT];
#pragma unroll
    for (int i = 0; i < QPT; ++i) {
        int qi = qbase + i * BLOCK;
        float qv = (qi < n_q) ? q[qi] : 0.f;
        q2[i] = (v2f){qv, qv};
        num2[i] = (v2f){0.f, 0.f};
        den2[i] = (v2f){0.f, 0.f};
    }

    const int seg_len = (n_t + segs - 1) / segs;
    const int s0 = seg * seg_len;
    const int s1 = min(s0 + seg_len, n_t);

    float* tA = (float*)tileA;
    float* tY = (float*)tileY;

    for (int base = s0; base < s1; base += TILE) {
        const int cnt = min(TILE, s1 - base);
        const int cnt2 = (cnt + 1) >> 1;
        __syncthreads();
        // all threads stage: one train point each (coalesced global reads)
        for (int l = tid; l < cnt; l += BLOCK) {
            int jj = base + l;
            float a = w[jj] * KFOLD;
            float nb = -xt[jj] * a;
            int p = l >> 1, h = l & 1;
            tA[p * 4 + h] = a;
            tA[p * 4 + 2 + h] = nb;
            tY[p * 2 + h] = yt[jj];
        }
        if (tid == 0 && (cnt & 1)) {   // pad odd tail: e = exp2(-1e8) = 0
            int p = cnt >> 1;
            tA[p * 4 + 1] = 0.f;
            tA[p * 4 + 3] = 1.0e4f;
            tY[p * 2 + 1] = 0.f;
        }
        __syncthreads();
#pragma unroll 4
        for (int j2 = 0; j2 < cnt2; ++j2) {
            float4 A = tileA[j2];
            float2 Y = tileY[j2];
            v2f a2 = (v2f){A.x, A.y};
            v2f nb2 = (v2f){A.z, A.w};
            v2f y2 = (v2f){Y.x, Y.y};
#pragma unroll
            for (int i = 0; i < QPT; ++i) {
                v2f t = __builtin_elementwise_fma(q2[i], a2, nb2);
                v2f s = -(t * t);            // v_pk_mul_f32 with neg mod
                v2f e = (v2f){EXP2F(s.x), EXP2F(s.y)};
                num2[i] = __builtin_elementwise_fma(e, y2, num2[i]);
                den2[i] = den2[i] + e;       // v_pk_add_f32
            }
        }
    }

#pragma unroll
    for (int i = 0; i < QPT; ++i) {
        int qi = qbase + i * BLOCK;
        if (qi < n_q)
            partial[seg * n_q + qi] =
                make_float2(num2[i].x + num2[i].y, den2[i].x + den2[i].y);
    }
}

// Block handles 64 queries; RSPLIT waves split the segs dimension so each
// wave's 64 lanes read 64 consecutive qi -> fully coalesced.
__global__ __launch_bounds__(BLOCK) void nw_reduce(
    const float2* __restrict__ partial, float* __restrict__ out,
    int n_q, int segs)
{
    __shared__ float2 red[RSPLIT][64];
    const int tid = threadIdx.x;
    const int c = tid >> 6;          // 0..3 (seg chunk = wave index)
    const int ql = tid & 63;         // query within block
    const int qi = blockIdx.x * 64 + ql;

    float num = 0.f, den = 0.f;
    if (qi < n_q) {
        for (int s = c; s < segs; s += RSPLIT) {
            float2 p = partial[(size_t)s * n_q + qi];
            num += p.x;
            den += p.y;
        }
    }
    red[c][ql] = make_float2(num, den);
    __syncthreads();
    if (c == 0 && qi < n_q) {
        float2 r1 = red[1][ql], r2 = red[2][ql], r3 = red[3][ql];
        num += r1.x + r2.x + r3.x;
        den += r1.y + r2.y + r3.y;
        out[qi] = num / den;
    }
}

extern "C" void kernel_launch(void* const* d_in, const int* in_sizes, int n_in,
                              void* d_out, int out_size, void* d_ws, size_t ws_size,
                              hipStream_t stream) {
    const float* q  = (const float*)d_in[0];
    const float* xt = (const float*)d_in[1];
    const float* yt = (const float*)d_in[2];
    const float* w  = (const float*)d_in[3];
    const int n_q = in_sizes[0];
    const int n_t = in_sizes[1];

    // split-K segments, clamped so partials fit in the workspace
    int segs = MAX_SEGS;
    size_t need = (size_t)segs * (size_t)n_q * sizeof(float2);
    if (need > ws_size) {
        segs = (int)(ws_size / ((size_t)n_q * sizeof(float2)));
        if (segs < 1) segs = 1;
    }

    float2* partial = (float2*)d_ws;
    dim3 grid(segs, (n_q + BLOCK * QPT - 1) / (BLOCK * QPT));
    nw_partial<<<grid, BLOCK, 0, stream>>>(q, xt, yt, w, partial, n_q, n_t, segs);
    nw_reduce<<<(n_q + 63) / 64, BLOCK, 0, stream>>>(partial, (float*)d_out,
                                                     n_q, segs);
}

// Round 8
// 104.420 us; speedup vs baseline: 1.1687x; 1.0072x over previous
//
#include <hip/hip_runtime.h>

#if defined(__has_builtin)
#if __has_builtin(__builtin_amdgcn_exp2f)
#define EXP2F(x) __builtin_amdgcn_exp2f(x)
#endif
#endif
#ifndef EXP2F
#define EXP2F(x) exp2f(x)
#endif

#define BLOCK 256
#define QPT 4          // queries per thread
#define TILE 512       // max train points staged per iteration
#define TILE2 (TILE / 2)
#define MAX_SEGS 128
#define RSPLIT 4       // seg-parallelism per query in the reduce

typedef float v2f __attribute__((ext_vector_type(2)));

// scores = -0.5*((q-x)*w)^2 ; fold sqrt(0.5*log2(e)) into w so exp2 applies
// directly: exp2(-(t*t)) with t = fma(q, a, nb), a = w*K, nb = -x*w*K.
#define KFOLD 0.8493218f  // sqrt(0.5 * log2(e))

// 8 blocks/CU (8 waves/SIMD) to hide per-wave exp dependency chains.
__global__ __launch_bounds__(BLOCK, 8) void nw_partial(
    const float* __restrict__ q, const float* __restrict__ xt,
    const float* __restrict__ yt, const float* __restrict__ w,
    float2* __restrict__ partial, int n_q, int n_t, int segs)
{
    // SoA pair layout: ds_read_b128 yields {a0,a1},{nb0,nb1} aligned for
    // v_pk_fma_f32; ds_read_b64 yields {y0,y1} for the packed accumulate.
    __shared__ float4 tileA[TILE2];   // {a_j, a_j+1, nb_j, nb_j+1}
    __shared__ float2 tileY[TILE2];   // {y_j, y_j+1}

    const int seg = blockIdx.x;
    const int tid = threadIdx.x;
    const int qbase = blockIdx.y * (BLOCK * QPT) + tid;

    v2f q2[QPT];       // {q_i, q_i} splat, loop-invariant
    v2f num2[QPT], den2[QPT];
#pragma unroll
    for (int i = 0; i < QPT; ++i) {
        int qi = qbase + i * BLOCK;
        float qv = (qi < n_q) ? q[qi] : 0.f;
        q2[i] = (v2f){qv, qv};
        num2[i] = (v2f){0.f, 0.f};
        den2[i] = (v2f){0.f, 0.f};
    }

    const int seg_len = (n_t + segs - 1) / segs;
    const int s0 = seg * seg_len;
    const int s1 = min(s0 + seg_len, n_t);

    float* tA = (float*)tileA;
    float* tY = (float*)tileY;

    for (int base = s0; base < s1; base += TILE) {
        const int cnt = min(TILE, s1 - base);
        const int cnt2 = (cnt + 1) >> 1;
        __syncthreads();
        for (int l = tid; l < cnt; l += BLOCK) {
            int jj = base + l;
            float a = w[jj] * KFOLD;
            float nb = -xt[jj] * a;
            int p = l >> 1, h = l & 1;
            tA[p * 4 + h] = a;
            tA[p * 4 + 2 + h] = nb;
            tY[p * 2 + h] = yt[jj];
        }
        if (tid == 0 && (cnt & 1)) {   // pad odd tail: e = exp2(-1e8) = 0
            int p = cnt >> 1;
            tA[p * 4 + 1] = 0.f;
            tA[p * 4 + 3] = 1.0e4f;
            tY[p * 2 + 1] = 0.f;
        }
        __syncthreads();
#pragma unroll 4
        for (int j2 = 0; j2 < cnt2; ++j2) {
            float4 A = tileA[j2];
            float2 Y = tileY[j2];
            v2f a2 = (v2f){A.x, A.y};
            v2f nb2 = (v2f){A.z, A.w};
            v2f y2 = (v2f){Y.x, Y.y};
#pragma unroll
            for (int i = 0; i < QPT; ++i) {
                v2f t = __builtin_elementwise_fma(q2[i], a2, nb2);
                v2f s = -(t * t);            // v_pk_mul_f32 with neg mod
                v2f e = (v2f){EXP2F(s.x), EXP2F(s.y)};
                num2[i] = __builtin_elementwise_fma(e, y2, num2[i]);
                den2[i] = den2[i] + e;       // v_pk_add_f32
            }
        }
    }

#pragma unroll
    for (int i = 0; i < QPT; ++i) {
        int qi = qbase + i * BLOCK;
        if (qi < n_q)
            partial[seg * n_q + qi] =
                make_float2(num2[i].x + num2[i].y, den2[i].x + den2[i].y);
    }
}

// Block handles 64 queries; RSPLIT waves split the segs dimension so each
// wave's 64 lanes read 64 consecutive qi -> fully coalesced.
__global__ __launch_bounds__(BLOCK) void nw_reduce(
    const float2* __restrict__ partial, float* __restrict__ out,
    int n_q, int segs)
{
    __shared__ float2 red[RSPLIT][64];
    const int tid = threadIdx.x;
    const int c = tid >> 6;          // 0..3 (seg chunk = wave index)
    const int ql = tid & 63;         // query within block
    const int qi = blockIdx.x * 64 + ql;

    float num = 0.f, den = 0.f;
    if (qi < n_q) {
        for (int s = c; s < segs; s += RSPLIT) {
            float2 p = partial[(size_t)s * n_q + qi];
            num += p.x;
            den += p.y;
        }
    }
    red[c][ql] = make_float2(num, den);
    __syncthreads();
    if (c == 0 && qi < n_q) {
        float2 r1 = red[1][ql], r2 = red[2][ql], r3 = red[3][ql];
        num += r1.x + r2.x + r3.x;
        den += r1.y + r2.y + r3.y;
        out[qi] = num / den;
    }
}

extern "C" void kernel_launch(void* const* d_in, const int* in_sizes, int n_in,
                              void* d_out, int out_size, void* d_ws, size_t ws_size,
                              hipStream_t stream) {
    const float* q  = (const float*)d_in[0];
    const float* xt = (const float*)d_in[1];
    const float* yt = (const float*)d_in[2];
    const float* w  = (const float*)d_in[3];
    const int n_q = in_sizes[0];
    const int n_t = in_sizes[1];

    // split-K segments, clamped so partials fit in the workspace
    int segs = MAX_SEGS;
    size_t need = (size_t)segs * (size_t)n_q * sizeof(float2);
    if (need > ws_size) {
        segs = (int)(ws_size / ((size_t)n_q * sizeof(float2)));
        if (segs < 1) segs = 1;
    }

    float2* partial = (float2*)d_ws;
    dim3 grid(segs, (n_q + BLOCK * QPT - 1) / (BLOCK * QPT));
    nw_partial<<<grid, BLOCK, 0, stream>>>(q, xt, yt, w, partial, n_q, n_t, segs);
    nw_reduce<<<(n_q + 63) / 64, BLOCK, 0, stream>>>(partial, (float*)d_out,
                                                     n_q, segs);
}